// Round 10
// baseline (155.478 us; speedup 1.0000x reference)
//
#include <hip/hip_runtime.h>

namespace {

typedef unsigned int uint;
typedef unsigned short ushort_t;
typedef __attribute__((ext_vector_type(8))) short bf16x8;
typedef __attribute__((ext_vector_type(4))) float f32x4;

constexpr int N = 4, T = 2048, L = 2048;
constexpr int DQIN = 32, DQK = 64;

// workspace layout (float-sized slots); ~12.8 MB
constexpr int VI_SZ = 3 * N * 64 * L;  // ushort pairs [dim row][8l-group][hi8|lo8], as float slots
constexpr int X_SZ = 3 * N * L;
constexpr int A_SZ = 3 * N * T;

union PK8 { int i[4]; bf16x8 s; };

// =================== fused prep kernel ===================
// [0,96): Q->a,g (one thread per (m,n,t)); [96,192): binary searches; [192,576): V transform
__global__ __launch_bounds__(256) void mm_prep(
    const float* __restrict__ ref_data, const float* __restrict__ ref_t,
    const float* __restrict__ d1, const float* __restrict__ t1,
    const float* __restrict__ d2, const float* __restrict__ t2,
    const float* __restrict__ d3, const float* __restrict__ t3,
    const float* __restrict__ Wq,
    const float* __restrict__ Wk1, const float* __restrict__ bk1,
    const float* __restrict__ Wv1, const float* __restrict__ bv1, const float* __restrict__ lt1,
    const float* __restrict__ Wk2, const float* __restrict__ bk2,
    const float* __restrict__ Wv2, const float* __restrict__ bv2, const float* __restrict__ lt2,
    const float* __restrict__ Wk3, const float* __restrict__ bk3,
    const float* __restrict__ Wv3, const float* __restrict__ bv3, const float* __restrict__ lt3,
    float* __restrict__ Aq, float* __restrict__ Gq, int* __restrict__ Cq,
    ushort_t* __restrict__ VI, float* __restrict__ X) {
  const int b = blockIdx.x;
  const int tid = threadIdx.x;

  if (b < 96) {
    // ---- Q path, one thread per (m, n*T+t); block-uniform modality m = b/32 ----
    const int m = b >> 5;
    const int idx = (b & 31) * 256 + tid;  // n*T + t
    __shared__ float sWq[DQIN * DQK];
    __shared__ float sWk[DQK];
    __shared__ float sbk[DQK];
    const float* Wk = (m == 0) ? Wk1 : (m == 1 ? Wk2 : Wk3);
    const float* bk = (m == 0) ? bk1 : (m == 1 ? bk2 : bk3);
    const float* lt = (m == 0) ? lt1 : (m == 1 ? lt2 : lt3);
    for (int i = tid; i < DQIN * DQK; i += 256) sWq[i] = Wq[i];
    if (tid < DQK) { sWk[tid] = Wk[tid]; sbk[tid] = bk[tid]; }
    __syncthreads();
    float x[DQIN];
    const float* rp = ref_data + idx * DQIN;
#pragma unroll
    for (int i = 0; i < DQIN; i++) x[i] = rp[i];
    float qr[DQK];
#pragma unroll
    for (int j = 0; j < DQK; j += 4) {
      float4 acc4 = make_float4(0.f, 0.f, 0.f, 0.f);
#pragma unroll
      for (int i = 0; i < DQIN; i++) {
        const float4 w = *(const float4*)&sWq[i * DQK + j];
        acc4.x = fmaf(x[i], w.x, acc4.x);
        acc4.y = fmaf(x[i], w.y, acc4.y);
        acc4.z = fmaf(x[i], w.z, acc4.z);
        acc4.w = fmaf(x[i], w.w, acc4.w);
      }
      qr[j] = acc4.x; qr[j + 1] = acc4.y; qr[j + 2] = acc4.z; qr[j + 3] = acc4.w;
    }
    const float rs = __expf(-0.5f * lt[0]);
    float g = 0.f, h = 0.f;
#pragma unroll
    for (int j = 1; j < DQK; j++) {
      g = fmaf(qr[j], sWk[j - 1], g);
      h = fmaf(qr[j], sbk[j - 1], h);
    }
    g += sWk[DQK - 1];
    h += sbk[DQK - 1];
    Aq[m * (N * T) + idx] = (qr[0] - h) * rs;
    Gq[m * (N * T) + idx] = g * rs;
  } else if (b < 192) {
    const int sidx = (b - 96) * 256 + tid;
    const int m = sidx >> 13;
    const int nt = sidx & 8191;
    const int n = nt >> 11;
    const float rt = ref_t[nt];
    const float* tml = ((m == 0) ? t1 : (m == 1 ? t2 : t3)) + n * L;
    int lo = 0, hi = L;
    while (lo < hi) {
      const int mid = (lo + hi) >> 1;
      if (tml[mid] <= rt) lo = mid + 1; else hi = mid;
    }
    Cq[m * 8192 + nt] = lo;
  } else {
    const int vb = b - 192;          // 0..383
    const int mn = vb >> 5;          // m*N+n
    const int m = mn >> 2, n = mn & 3;
    const int lseg0 = (vb & 31) * 64;
    const float* dm = (m == 0) ? d1 : (m == 1 ? d2 : d3);
    const float* Wv = (m == 0) ? Wv1 : (m == 1 ? Wv2 : Wv3);
    const float* bv = (m == 0) ? bv1 : (m == 1 ? bv2 : bv3);
    const int cdim = tid & 63;
    const int qq = tid >> 6;
    const int l0 = lseg0 + qq * 16;

    float Wc[32];
#pragma unroll
    for (int i = 0; i < 32; i++) Wc[i] = Wv[i * 64 + cdim];
    const float bvc = bv[cdim];

    uint hi16[16], lo16[16];
#pragma unroll 4
    for (int k = 0; k < 16; k++) {
      const float* dp = dm + (size_t)(n * L + l0 + k) * 34;
      float acc = bvc;
#pragma unroll
      for (int i = 0; i < 32; i++) acc = fmaf(dp[i], Wc[i], acc);
      uint u = __float_as_uint(acc);
      uint h = (u + 0x7fffu + ((u >> 16) & 1u)) & 0xffff0000u;
      float res = acc - __uint_as_float(h);
      uint ul = __float_as_uint(res);
      uint hl = (ul + 0x7fffu + ((ul >> 16) & 1u)) >> 16;
      hi16[k] = h >> 16;
      lo16[k] = hl;
    }
    int pkh[8], pkl[8];
#pragma unroll
    for (int p = 0; p < 8; p++) {
      pkh[p] = (int)(hi16[2 * p] | (hi16[2 * p + 1] << 16));
      pkl[p] = (int)(lo16[2 * p] | (lo16[2 * p + 1] << 16));
    }
    ushort_t* dst = VI + (size_t)(mn * 64 + cdim) * (2 * L) + (l0 >> 3) * 16;
    *(int4*)dst = make_int4(pkh[0], pkh[1], pkh[2], pkh[3]);
    *(int4*)(dst + 8) = make_int4(pkl[0], pkl[1], pkl[2], pkl[3]);
    *(int4*)(dst + 16) = make_int4(pkh[4], pkh[5], pkh[6], pkh[7]);
    *(int4*)(dst + 24) = make_int4(pkl[4], pkl[5], pkl[6], pkl[7]);

    if (tid < 64) {
      const int l = lseg0 + tid;
      X[mn * L + l] = dm[(size_t)(n * L + l) * 34 + 33];
    }
  }
}

// =================== main attention kernel ===================
// block = 2 waves x 32 output dims (dh selects dim half). Waves handle the
// SIMILAR-c rowgroup pair {2p, 2p+1} (c differs by <=~32 l -> both waves run
// nearly the same chunk count; no barrier idle). Block work ~ c(pair); dispatch
// order alternates heavy/light pairs so each CU's resident set sums ~constant.
// Per 64-l chunk the block stages an 8 KB V-slab into double-buffered LDS via
// global_load_lds; X cached in LDS once per block. exp dup = 2 (dim halves)
// traded for 6 blocks/CU = 12 waves/CU concurrency.
__device__ inline void stage_chunk(ushort_t* dstbuf, const ushort_t* VIb, int ch,
                                   int w, int lane) {
#pragma unroll
  for (int i = 0; i < 4; i++) {
    const int u = (w * 4 + i) * 64 + lane;   // 16B-unit index 0..511
    const int lr = u >> 4;                   // local dim row 0..31
    const int gs = u & 15;                   // swizzled unit slot
    const int g = (gs - lr) & 15;            // original unit (8l-halfpair, hi/lo)
    const ushort_t* src = VIb + (size_t)lr * 4096 + ch * 128 + g * 8;
    __builtin_amdgcn_global_load_lds(
        (const __attribute__((address_space(1))) void*)src,
        (__attribute__((address_space(3))) void*)(dstbuf + (w * 4 + i) * 512),
        16, 0, 0);
  }
}

__global__ __launch_bounds__(128, 3) void mm_attn_main(
    const ushort_t* __restrict__ VI, const float* __restrict__ X,
    const float* __restrict__ Aq, const float* __restrict__ Gq, const int* __restrict__ Cq,
    float* __restrict__ out) {
  __shared__ ushort_t sbuf[2][4096];  // 2 x 8KB V slabs
  __shared__ float sx[2048];          // full X row for this mn (8KB)  -> 24KB total

  const int b = blockIdx.x;
  const int mn = b % 12;
  const int rr0 = b / 12;  // 0..127
  const int dh = rr0 & 1;  // dim half
  const int j = rr0 >> 1;  // 0..63
  // alternate heavy/light pairs across consecutive blockIdx (heavy = high pair idx)
  const int pj = (j & 1) ? (j >> 1) : (63 - (j >> 1));

  const int tid = threadIdx.x;
  const int lane = tid & 63;
  const int w = tid >> 6;              // wave 0/1
  const int q = lane >> 4;
  const int m16 = lane & 15;

  const int rg = pj * 2 + w;           // similar-c pair {2pj, 2pj+1}
  const int tbase = mn * T + rg * 16;

  const int c = Cq[tbase + m16];
  const int cmax = __shfl(c, 15, 64);  // c monotone in t
  const int cmin = __shfl(c, 0, 64);
  const int nch = (cmax + 63) >> 6;    // this wave's chunk count

  // block-uniform chunk count: pair's max c = last row of rowgroup 2pj+1
  const int cB = Cq[mn * T + (pj * 2 + 1) * 16 + 15];
  const int nchB = (cB + 63) >> 6;

  const float a = Aq[tbase + m16];
  const float g = Gq[tbase + m16];

  f32x4 acc[2];
  acc[0] = (f32x4){0.f, 0.f, 0.f, 0.f};
  acc[1] = (f32x4){0.f, 0.f, 0.f, 0.f};
  float z = 0.f;

  const ushort_t* VIb = VI + (size_t)(mn * 64 + dh * 32) * 4096;
  const float* xg = X + mn * L;

  // hoisted swizzled B-fragment offsets (shorts), loop-invariant per lane:
  // unit (lr, gg) at lr*16 + ((gg+lr)&15); gg = kk*8 + q*2 + hl
  int oh[2][2], ol[2][2];
#pragma unroll
  for (int ct = 0; ct < 2; ct++) {
#pragma unroll
    for (int kk = 0; kk < 2; kk++) {
      const int lr = ct * 16 + m16;
      oh[ct][kk] = lr * 128 + (((kk * 8 + q * 2 + 0) + lr) & 15) * 8;
      ol[ct][kk] = lr * 128 + (((kk * 8 + q * 2 + 1) + lr) & 15) * 8;
    }
  }

  // stage X (8 instrs of 1KB across the block) + first V chunk
#pragma unroll
  for (int i = 0; i < 4; i++) {
    const float* src = xg + (w * 4 + i) * 256 + lane * 4;
    __builtin_amdgcn_global_load_lds(
        (const __attribute__((address_space(1))) void*)src,
        (__attribute__((address_space(3))) void*)(sx + (w * 4 + i) * 256),
        16, 0, 0);
  }
  stage_chunk(sbuf[0], VIb, 0, w, lane);
  __syncthreads();

  for (int ch = 0; ch < nchB; ch++) {
    const int nb = ch & 1;
    if (ch + 1 < nchB) stage_chunk(sbuf[nb ^ 1], VIb, ch + 1, w, lane);

    if (ch < nch) {
      const int base = ch << 6;
      const ushort_t* buf = sbuf[nb];
      const bool inter = (base + 64 <= cmin);  // all 16 rows fully active
#pragma unroll
      for (int kk = 0; kk < 2; kk++) {
        const int k0 = base + kk * 32 + q * 8;
        const float4 xa = *(const float4*)&sx[k0];
        const float4 xb = *(const float4*)&sx[k0 + 4];
        const float xs[8] = {xa.x, xa.y, xa.z, xa.w, xb.x, xb.y, xb.z, xb.w};
        float wv[8];
        if (inter) {
#pragma unroll
          for (int jj = 0; jj < 8; jj++) {
            const float d = fmaf(-g, xs[jj], a);
            wv[jj] = __expf(-d * d);
            z += wv[jj];
          }
        } else {
#pragma unroll
          for (int jj = 0; jj < 8; jj++) {
            const float d = fmaf(-g, xs[jj], a);
            const float e = __expf(-d * d);
            wv[jj] = (k0 + jj < c) ? e : 0.f;
            z += wv[jj];
          }
        }
        PK8 ph, pl;
#pragma unroll
        for (int p2 = 0; p2 < 4; p2++) {
          const uint u0 = __float_as_uint(wv[2 * p2]);
          const uint u1 = __float_as_uint(wv[2 * p2 + 1]);
          const uint h0 = u0 & 0xffff0000u, h1 = u1 & 0xffff0000u;
          const float l0f = wv[2 * p2] - __uint_as_float(h0);
          const float l1f = wv[2 * p2 + 1] - __uint_as_float(h1);
          ph.i[p2] = (int)((h0 >> 16) | h1);
          pl.i[p2] = (int)((__float_as_uint(l0f) >> 16) | (__float_as_uint(l1f) & 0xffff0000u));
        }
        const bf16x8 ahi = ph.s, alo = pl.s;
#pragma unroll
        for (int ct = 0; ct < 2; ct++) {
          const bf16x8 bh = *(const bf16x8*)(buf + oh[ct][kk]);
          const bf16x8 bl = *(const bf16x8*)(buf + ol[ct][kk]);
          acc[ct] = __builtin_amdgcn_mfma_f32_16x16x32_bf16(ahi, bh, acc[ct], 0, 0, 0);
          acc[ct] = __builtin_amdgcn_mfma_f32_16x16x32_bf16(ahi, bl, acc[ct], 0, 0, 0);
          acc[ct] = __builtin_amdgcn_mfma_f32_16x16x32_bf16(alo, bh, acc[ct], 0, 0, 0);
        }
      }
    }
    __syncthreads();  // reads of buf done + staging of nb^1 complete
  }

  // z: reduce q-replicas (each octet covered disjoint l)
  z += __shfl_xor(z, 16, 64);
  z += __shfl_xor(z, 32, 64);

  // D layout per ct: col = dh*32 + ct*16 + m16, row = q*4 + rr
#pragma unroll
  for (int rr = 0; rr < 4; rr++) {
    const int row = q * 4 + rr;
    const float zr = __shfl(z, row, 64);
    const int cr = __shfl(c, row, 64);
    const float inv = 1.0f / (zr + (float)(L - cr));
#pragma unroll
    for (int ct = 0; ct < 2; ct++) {
      out[(size_t)(tbase + row) * 64 + dh * 32 + ct * 16 + m16] = acc[ct][rr] * inv;
    }
  }
}

}  // namespace

extern "C" void kernel_launch(void* const* d_in, const int* in_sizes, int n_in,
                              void* d_out, int out_size, void* d_ws, size_t ws_size,
                              hipStream_t stream) {
  const float* ref_data = (const float*)d_in[0];
  const float* ref_t = (const float*)d_in[1];
  const float* m1_data = (const float*)d_in[2];
  const float* m1_t = (const float*)d_in[3];
  const float* m2_data = (const float*)d_in[4];
  const float* m2_t = (const float*)d_in[5];
  const float* m3_data = (const float*)d_in[6];
  const float* m3_t = (const float*)d_in[7];
  const float* Wq = (const float*)d_in[8];
  const float* Wk1 = (const float*)d_in[9];
  const float* bk1 = (const float*)d_in[10];
  const float* Wv1 = (const float*)d_in[11];
  const float* bv1 = (const float*)d_in[12];
  const float* lt1 = (const float*)d_in[13];
  const float* Wk2 = (const float*)d_in[14];
  const float* bk2 = (const float*)d_in[15];
  const float* Wv2 = (const float*)d_in[16];
  const float* bv2 = (const float*)d_in[17];
  const float* lt2 = (const float*)d_in[18];
  const float* Wk3 = (const float*)d_in[19];
  const float* bk3 = (const float*)d_in[20];
  const float* Wv3 = (const float*)d_in[21];
  const float* bv3 = (const float*)d_in[22];
  const float* lt3 = (const float*)d_in[23];

  float* ws = (float*)d_ws;
  ushort_t* VI = (ushort_t*)ws;                 // VI_SZ float slots
  float* Xw = ws + VI_SZ;                       // X_SZ
  float* Aq = Xw + X_SZ;                        // A_SZ
  float* Gq = Aq + A_SZ;                        // A_SZ
  int* Cq = (int*)(Gq + A_SZ);                  // A_SZ

  mm_prep<<<dim3(576), dim3(256), 0, stream>>>(
      ref_data, ref_t, m1_data, m1_t, m2_data, m2_t, m3_data, m3_t, Wq,
      Wk1, bk1, Wv1, bv1, lt1, Wk2, bk2, Wv2, bv2, lt2, Wk3, bk3, Wv3, bv3, lt3,
      Aq, Gq, Cq, VI, Xw);
  mm_attn_main<<<dim3(12 * 64 * 2), dim3(128), 0, stream>>>(
      VI, Xw, Aq, Gq, Cq, (float*)d_out);
}

// Round 11
// 147.507 us; speedup vs baseline: 1.0540x; 1.0540x over previous
//
#include <hip/hip_runtime.h>

namespace {

typedef unsigned int uint;
typedef unsigned short ushort_t;
typedef __attribute__((ext_vector_type(8))) short bf16x8;
typedef __attribute__((ext_vector_type(4))) float f32x4;

constexpr int N = 4, T = 2048, L = 2048;
constexpr int DQIN = 32, DQK = 64;

// workspace layout (float-sized slots); ~12.8 MB
constexpr int VI_SZ = 3 * N * 64 * L;  // ushort pairs [dim row][8l-group][hi8|lo8], as float slots
constexpr int X_SZ = 3 * N * L;
constexpr int A_SZ = 3 * N * T;

union PK8 { int i[4]; bf16x8 s; };

// =================== fused prep kernel ===================
// [0,96): Q->a,g (one thread per (m,n,t)); [96,192): binary searches; [192,576): V transform
__global__ __launch_bounds__(256) void mm_prep(
    const float* __restrict__ ref_data, const float* __restrict__ ref_t,
    const float* __restrict__ d1, const float* __restrict__ t1,
    const float* __restrict__ d2, const float* __restrict__ t2,
    const float* __restrict__ d3, const float* __restrict__ t3,
    const float* __restrict__ Wq,
    const float* __restrict__ Wk1, const float* __restrict__ bk1,
    const float* __restrict__ Wv1, const float* __restrict__ bv1, const float* __restrict__ lt1,
    const float* __restrict__ Wk2, const float* __restrict__ bk2,
    const float* __restrict__ Wv2, const float* __restrict__ bv2, const float* __restrict__ lt2,
    const float* __restrict__ Wk3, const float* __restrict__ bk3,
    const float* __restrict__ Wv3, const float* __restrict__ bv3, const float* __restrict__ lt3,
    float* __restrict__ Aq, float* __restrict__ Gq, int* __restrict__ Cq,
    ushort_t* __restrict__ VI, float* __restrict__ X) {
  const int b = blockIdx.x;
  const int tid = threadIdx.x;

  if (b < 96) {
    // ---- Q path, one thread per (m, n*T+t); block-uniform modality m = b/32 ----
    const int m = b >> 5;
    const int idx = (b & 31) * 256 + tid;  // n*T + t
    __shared__ float sWq[DQIN * DQK];
    __shared__ float sWk[DQK];
    __shared__ float sbk[DQK];
    const float* Wk = (m == 0) ? Wk1 : (m == 1 ? Wk2 : Wk3);
    const float* bk = (m == 0) ? bk1 : (m == 1 ? bk2 : bk3);
    const float* lt = (m == 0) ? lt1 : (m == 1 ? lt2 : lt3);
    for (int i = tid; i < DQIN * DQK; i += 256) sWq[i] = Wq[i];
    if (tid < DQK) { sWk[tid] = Wk[tid]; sbk[tid] = bk[tid]; }
    __syncthreads();
    float x[DQIN];
    const float* rp = ref_data + idx * DQIN;
#pragma unroll
    for (int i = 0; i < DQIN; i++) x[i] = rp[i];
    float qr[DQK];
#pragma unroll
    for (int j = 0; j < DQK; j += 4) {
      float4 acc4 = make_float4(0.f, 0.f, 0.f, 0.f);
#pragma unroll
      for (int i = 0; i < DQIN; i++) {
        const float4 w = *(const float4*)&sWq[i * DQK + j];
        acc4.x = fmaf(x[i], w.x, acc4.x);
        acc4.y = fmaf(x[i], w.y, acc4.y);
        acc4.z = fmaf(x[i], w.z, acc4.z);
        acc4.w = fmaf(x[i], w.w, acc4.w);
      }
      qr[j] = acc4.x; qr[j + 1] = acc4.y; qr[j + 2] = acc4.z; qr[j + 3] = acc4.w;
    }
    const float rs = __expf(-0.5f * lt[0]);
    float g = 0.f, h = 0.f;
#pragma unroll
    for (int j = 1; j < DQK; j++) {
      g = fmaf(qr[j], sWk[j - 1], g);
      h = fmaf(qr[j], sbk[j - 1], h);
    }
    g += sWk[DQK - 1];
    h += sbk[DQK - 1];
    Aq[m * (N * T) + idx] = (qr[0] - h) * rs;
    Gq[m * (N * T) + idx] = g * rs;
  } else if (b < 192) {
    const int sidx = (b - 96) * 256 + tid;
    const int m = sidx >> 13;
    const int nt = sidx & 8191;
    const int n = nt >> 11;
    const float rt = ref_t[nt];
    const float* tml = ((m == 0) ? t1 : (m == 1 ? t2 : t3)) + n * L;
    int lo = 0, hi = L;
    while (lo < hi) {
      const int mid = (lo + hi) >> 1;
      if (tml[mid] <= rt) lo = mid + 1; else hi = mid;
    }
    Cq[m * 8192 + nt] = lo;
  } else {
    const int vb = b - 192;          // 0..383
    const int mn = vb >> 5;          // m*N+n
    const int m = mn >> 2, n = mn & 3;
    const int lseg0 = (vb & 31) * 64;
    const float* dm = (m == 0) ? d1 : (m == 1 ? d2 : d3);
    const float* Wv = (m == 0) ? Wv1 : (m == 1 ? Wv2 : Wv3);
    const float* bv = (m == 0) ? bv1 : (m == 1 ? bv2 : bv3);
    const int cdim = tid & 63;
    const int qq = tid >> 6;
    const int l0 = lseg0 + qq * 16;

    float Wc[32];
#pragma unroll
    for (int i = 0; i < 32; i++) Wc[i] = Wv[i * 64 + cdim];
    const float bvc = bv[cdim];

    uint hi16[16], lo16[16];
#pragma unroll 4
    for (int k = 0; k < 16; k++) {
      const float* dp = dm + (size_t)(n * L + l0 + k) * 34;
      float acc = bvc;
#pragma unroll
      for (int i = 0; i < 32; i++) acc = fmaf(dp[i], Wc[i], acc);
      uint u = __float_as_uint(acc);
      uint h = (u + 0x7fffu + ((u >> 16) & 1u)) & 0xffff0000u;
      float res = acc - __uint_as_float(h);
      uint ul = __float_as_uint(res);
      uint hl = (ul + 0x7fffu + ((ul >> 16) & 1u)) >> 16;
      hi16[k] = h >> 16;
      lo16[k] = hl;
    }
    int pkh[8], pkl[8];
#pragma unroll
    for (int p = 0; p < 8; p++) {
      pkh[p] = (int)(hi16[2 * p] | (hi16[2 * p + 1] << 16));
      pkl[p] = (int)(lo16[2 * p] | (lo16[2 * p + 1] << 16));
    }
    ushort_t* dst = VI + (size_t)(mn * 64 + cdim) * (2 * L) + (l0 >> 3) * 16;
    *(int4*)dst = make_int4(pkh[0], pkh[1], pkh[2], pkh[3]);
    *(int4*)(dst + 8) = make_int4(pkl[0], pkl[1], pkl[2], pkl[3]);
    *(int4*)(dst + 16) = make_int4(pkh[4], pkh[5], pkh[6], pkh[7]);
    *(int4*)(dst + 24) = make_int4(pkl[4], pkl[5], pkl[6], pkl[7]);

    if (tid < 64) {
      const int l = lseg0 + tid;
      X[mn * L + l] = dm[(size_t)(n * L + l) * 34 + 33];
    }
  }
}

// =================== main attention kernel ===================
// block = 2 waves x 32 output dims (dh selects dim half); waves handle the
// similar-c rowgroup pair {2p, 2p+1}. 128-l chunks: per chunk the block stages
// a 16 KB V-slab (32 rows x 512 contiguous bytes each) into double-buffered
// LDS via global_load_lds; X cached in LDS once per block. 2 barriers per
// 128 l (vs per 64 l before) halves the vmcnt(0)-drain tax. LDS=40KB -> 4
// blocks/CU residency with 1536 grid -> 512-block refill queue; heavy blocks
// dispatched first (LPT) so the refill tail is light.
__device__ inline void stage_chunk(ushort_t* dstbuf, const ushort_t* VIb, int ch,
                                   int w, int lane) {
#pragma unroll
  for (int i = 0; i < 8; i++) {
    const int n = (w * 8 + i) * 64 + lane;   // lds 16B-unit index 0..1023
    const int lr = n >> 5;                   // local dim row 0..31
    const int slot = n & 31;                 // swizzled unit slot
    const int u = (slot - lr) & 31;          // original unit within row-chunk
    const ushort_t* src = VIb + (size_t)lr * 4096 + ch * 256 + u * 8;
    __builtin_amdgcn_global_load_lds(
        (const __attribute__((address_space(1))) void*)src,
        (__attribute__((address_space(3))) void*)(dstbuf + (w * 8 + i) * 512),
        16, 0, 0);
  }
}

__global__ __launch_bounds__(128, 2) void mm_attn_main(
    const ushort_t* __restrict__ VI, const float* __restrict__ X,
    const float* __restrict__ Aq, const float* __restrict__ Gq, const int* __restrict__ Cq,
    float* __restrict__ out) {
  __shared__ ushort_t sbuf[2][8192];  // 2 x 16KB V slabs
  __shared__ float sx[2048];          // full X row for this mn (8KB) -> 40KB total

  const int b = blockIdx.x;
  const int mn = b % 12;
  const int rr0 = b / 12;  // 0..127
  const int dh = rr0 & 1;  // dim half
  const int j = rr0 >> 1;  // 0..63
  const int pj = 63 - j;   // heavy pairs (large c) first in dispatch order

  const int tid = threadIdx.x;
  const int lane = tid & 63;
  const int w = tid >> 6;              // wave 0/1
  const int q = lane >> 4;
  const int m16 = lane & 15;

  const int rg = pj * 2 + w;           // similar-c pair {2pj, 2pj+1}
  const int tbase = mn * T + rg * 16;

  const int c = Cq[tbase + m16];
  const int cmax = __shfl(c, 15, 64);  // c monotone in t
  const int cmin = __shfl(c, 0, 64);
  const int nch = (cmax + 127) >> 7;   // this wave's 128-l chunk count

  // block-uniform chunk count: pair's max c = last row of rowgroup 2pj+1
  const int cB = Cq[mn * T + (pj * 2 + 1) * 16 + 15];
  const int nchB = (cB + 127) >> 7;

  const float a = Aq[tbase + m16];
  const float g = Gq[tbase + m16];

  f32x4 acc[2];
  acc[0] = (f32x4){0.f, 0.f, 0.f, 0.f};
  acc[1] = (f32x4){0.f, 0.f, 0.f, 0.f};
  float z = 0.f;

  const ushort_t* VIb = VI + (size_t)(mn * 64 + dh * 32) * 4096;
  const float* xg = X + mn * L;

  // hoisted swizzled B-fragment byte offsets (in ushorts), loop-invariant per lane:
  // unit (lr, u) at lr*32 + ((u+lr)&31); u = (kk*4+q)*2 + hl, kk in 0..3
  int oh[2][4], ol[2][4];
#pragma unroll
  for (int ct = 0; ct < 2; ct++) {
#pragma unroll
    for (int kk = 0; kk < 4; kk++) {
      const int lr = ct * 16 + m16;
      const int uh = (kk * 4 + q) * 2;
      oh[ct][kk] = lr * 256 + (((uh + 0) + lr) & 31) * 8;
      ol[ct][kk] = lr * 256 + (((uh + 1) + lr) & 31) * 8;
    }
  }

  // stage X (8 instrs of 1KB across the block) + first V chunk
#pragma unroll
  for (int i = 0; i < 4; i++) {
    const float* src = xg + (w * 4 + i) * 256 + lane * 4;
    __builtin_amdgcn_global_load_lds(
        (const __attribute__((address_space(1))) void*)src,
        (__attribute__((address_space(3))) void*)(sx + (w * 4 + i) * 256),
        16, 0, 0);
  }
  stage_chunk(sbuf[0], VIb, 0, w, lane);
  __syncthreads();

  for (int ch = 0; ch < nchB; ch++) {
    const int nb = ch & 1;
    if (ch + 1 < nchB) stage_chunk(sbuf[nb ^ 1], VIb, ch + 1, w, lane);

    if (ch < nch) {
      const int base = ch << 7;
      const ushort_t* buf = sbuf[nb];
      const bool inter = (base + 128 <= cmin);  // all 16 rows fully active
#pragma unroll
      for (int kk = 0; kk < 4; kk++) {
        const int k0 = base + kk * 32 + q * 8;
        const float4 xa = *(const float4*)&sx[k0];
        const float4 xb = *(const float4*)&sx[k0 + 4];
        const float xs[8] = {xa.x, xa.y, xa.z, xa.w, xb.x, xb.y, xb.z, xb.w};
        float wv[8];
        if (inter) {
#pragma unroll
          for (int jj = 0; jj < 8; jj++) {
            const float d = fmaf(-g, xs[jj], a);
            wv[jj] = __expf(-d * d);
            z += wv[jj];
          }
        } else {
#pragma unroll
          for (int jj = 0; jj < 8; jj++) {
            const float d = fmaf(-g, xs[jj], a);
            const float e = __expf(-d * d);
            wv[jj] = (k0 + jj < c) ? e : 0.f;
            z += wv[jj];
          }
        }
        PK8 ph, pl;
#pragma unroll
        for (int p2 = 0; p2 < 4; p2++) {
          const uint u0 = __float_as_uint(wv[2 * p2]);
          const uint u1 = __float_as_uint(wv[2 * p2 + 1]);
          const uint h0 = u0 & 0xffff0000u, h1 = u1 & 0xffff0000u;
          const float l0f = wv[2 * p2] - __uint_as_float(h0);
          const float l1f = wv[2 * p2 + 1] - __uint_as_float(h1);
          ph.i[p2] = (int)((h0 >> 16) | h1);
          pl.i[p2] = (int)((__float_as_uint(l0f) >> 16) | (__float_as_uint(l1f) & 0xffff0000u));
        }
        const bf16x8 ahi = ph.s, alo = pl.s;
#pragma unroll
        for (int ct = 0; ct < 2; ct++) {
          const bf16x8 bh = *(const bf16x8*)(buf + oh[ct][kk]);
          const bf16x8 bl = *(const bf16x8*)(buf + ol[ct][kk]);
          acc[ct] = __builtin_amdgcn_mfma_f32_16x16x32_bf16(ahi, bh, acc[ct], 0, 0, 0);
          acc[ct] = __builtin_amdgcn_mfma_f32_16x16x32_bf16(ahi, bl, acc[ct], 0, 0, 0);
          acc[ct] = __builtin_amdgcn_mfma_f32_16x16x32_bf16(alo, bh, acc[ct], 0, 0, 0);
        }
      }
    }
    __syncthreads();  // reads of buf done + staging of nb^1 complete
  }

  // z: reduce q-replicas (each octet covered disjoint l)
  z += __shfl_xor(z, 16, 64);
  z += __shfl_xor(z, 32, 64);

  // D layout per ct: col = dh*32 + ct*16 + m16, row = q*4 + rr
#pragma unroll
  for (int rr = 0; rr < 4; rr++) {
    const int row = q * 4 + rr;
    const float zr = __shfl(z, row, 64);
    const int cr = __shfl(c, row, 64);
    const float inv = 1.0f / (zr + (float)(L - cr));
#pragma unroll
    for (int ct = 0; ct < 2; ct++) {
      out[(size_t)(tbase + row) * 64 + dh * 32 + ct * 16 + m16] = acc[ct][rr] * inv;
    }
  }
}

}  // namespace

extern "C" void kernel_launch(void* const* d_in, const int* in_sizes, int n_in,
                              void* d_out, int out_size, void* d_ws, size_t ws_size,
                              hipStream_t stream) {
  const float* ref_data = (const float*)d_in[0];
  const float* ref_t = (const float*)d_in[1];
  const float* m1_data = (const float*)d_in[2];
  const float* m1_t = (const float*)d_in[3];
  const float* m2_data = (const float*)d_in[4];
  const float* m2_t = (const float*)d_in[5];
  const float* m3_data = (const float*)d_in[6];
  const float* m3_t = (const float*)d_in[7];
  const float* Wq = (const float*)d_in[8];
  const float* Wk1 = (const float*)d_in[9];
  const float* bk1 = (const float*)d_in[10];
  const float* Wv1 = (const float*)d_in[11];
  const float* bv1 = (const float*)d_in[12];
  const float* lt1 = (const float*)d_in[13];
  const float* Wk2 = (const float*)d_in[14];
  const float* bk2 = (const float*)d_in[15];
  const float* Wv2 = (const float*)d_in[16];
  const float* bv2 = (const float*)d_in[17];
  const float* lt2 = (const float*)d_in[18];
  const float* Wk3 = (const float*)d_in[19];
  const float* bk3 = (const float*)d_in[20];
  const float* Wv3 = (const float*)d_in[21];
  const float* bv3 = (const float*)d_in[22];
  const float* lt3 = (const float*)d_in[23];

  float* ws = (float*)d_ws;
  ushort_t* VI = (ushort_t*)ws;                 // VI_SZ float slots
  float* Xw = ws + VI_SZ;                       // X_SZ
  float* Aq = Xw + X_SZ;                        // A_SZ
  float* Gq = Aq + A_SZ;                        // A_SZ
  int* Cq = (int*)(Gq + A_SZ);                  // A_SZ

  mm_prep<<<dim3(576), dim3(256), 0, stream>>>(
      ref_data, ref_t, m1_data, m1_t, m2_data, m2_t, m3_data, m3_t, Wq,
      Wk1, bk1, Wv1, bv1, lt1, Wk2, bk2, Wv2, bv2, lt2, Wk3, bk3, Wv3, bv3, lt3,
      Aq, Gq, Cq, VI, Xw);
  mm_attn_main<<<dim3(12 * 64 * 2), dim3(128), 0, stream>>>(
      VI, Xw, Aq, Gq, Cq, (float*)d_out);
}